// Round 4
// baseline (401.784 us; speedup 1.0000x reference)
//
#include <hip/hip_runtime.h>
#include <stdint.h>

#define NB 32
#define C_ 128
#define H_ 56
#define W_ 56
#define HW 3136
#define KD 384

typedef __attribute__((ext_vector_type(8))) short bf16x8;
typedef __attribute__((ext_vector_type(4))) float f32x4;

__device__ inline uint16_t f2bf(float f) {
    uint32_t u = __float_as_uint(f);
    return (uint16_t)((u + 0x7FFFu + ((u >> 16) & 1u)) >> 16);
}
__device__ inline float bf2f(uint16_t b) {
    return __uint_as_float(((uint32_t)b) << 16);
}

// ---------------------------------------------------------------------------
// P1: x (f32) -> xtp bf16 [n][h][w(64,pad0)][c]   (transposed for K1 B-operand)
// ---------------------------------------------------------------------------
__global__ __launch_bounds__(256) void p1_xtp(const float* __restrict__ x,
                                              uint16_t* __restrict__ xtp) {
    __shared__ uint16_t lt[56][136];
    const int h = blockIdx.x, n = blockIdx.y, tid = threadIdx.x;
    const int c = tid >> 1, wh = tid & 1;
    const float* xr = &x[(((size_t)n * C_ + c) * H_ + h) * W_ + wh * 28];
#pragma unroll
    for (int q = 0; q < 7; ++q) {
        float4 v = *(const float4*)&xr[q * 4];
        int wb = wh * 28 + q * 4;
        lt[wb + 0][c] = f2bf(v.x);
        lt[wb + 1][c] = f2bf(v.y);
        lt[wb + 2][c] = f2bf(v.z);
        lt[wb + 3][c] = f2bf(v.w);
    }
    __syncthreads();
    const int w = tid >> 2, qc = tid & 3;   // each thread owns 32 halves
    uint16_t* dst = &xtp[((((size_t)n * H_ + h) * 64 + w)) * C_ + qc * 32];
    if (w < 56) {
        const uint32_t* s = (const uint32_t*)&lt[w][qc * 32];
        uint4 a = *(const uint4*)(s);
        uint4 b = *(const uint4*)(s + 4);
        uint4 c4 = *(const uint4*)(s + 8);
        uint4 d4 = *(const uint4*)(s + 12);
        *(uint4*)dst = a;
        *(uint4*)(dst + 8) = b;
        *(uint4*)(dst + 16) = c4;
        *(uint4*)(dst + 24) = d4;
    } else {
        uint4 z = {0, 0, 0, 0};
        *(uint4*)dst = z;
        *(uint4*)(dst + 8) = z;
        *(uint4*)(dst + 16) = z;
        *(uint4*)(dst + 24) = z;
    }
}

// ---------------------------------------------------------------------------
// P2: p3 (f32 [c][3c2+tap]) -> ap bf16 [c][d'] with d' = tap*128 + c2
// ---------------------------------------------------------------------------
__global__ __launch_bounds__(256) void p2_ap(const float* __restrict__ p3,
                                             uint16_t* __restrict__ ap) {
    int i = blockIdx.x * 256 + threadIdx.x;  // < 49152
    int c = i / KD, dp = i - c * KD;
    int tap = dp >> 7, c2 = dp & 127;
    ap[i] = f2bf(p3[c * KD + 3 * c2 + tap]);
}

// ---------------------------------------------------------------------------
// K1: t3[c][w] = sum_{d'} ap[c][d'] * xtp[n][h+2(tap-1)][w][c2]   (MFMA)
// writes bf16 t3b[n][c][h][w64] (w 56..63 zero)
// ---------------------------------------------------------------------------
__global__ __launch_bounds__(256) void k1(const uint16_t* __restrict__ xtp,
                                          const uint16_t* __restrict__ ap,
                                          uint16_t* __restrict__ t3b) {
    __shared__ uint16_t smem[3 * 64 * 128];  // 48 KB; reused as lrow[128][72]
    const int h = blockIdx.x, n = blockIdx.y, tid = threadIdx.x;
    const int lane = tid & 63, wid = tid >> 6;
    const int wm = wid >> 1, wn = wid & 1;

    // stage B: 3 taps x 64 w-rows x 16 chunks (chunk-XOR swizzled, 256B rows)
    for (int t = tid; t < 3072; t += 256) {
        int tap = t >> 10, r = t & 1023, w = r >> 4, qp = r & 15;
        int q = qp ^ (w & 7);
        int hh = h + 2 * (tap - 1);
        uint4 v = {0, 0, 0, 0};
        if ((unsigned)hh < (unsigned)H_)
            v = *(const uint4*)&xtp[((((size_t)n * H_ + hh) * 64 + w)) * C_ + q * 8];
        *(uint4*)&smem[tap * 8192 + w * 128 + qp * 8] = v;
    }
    __syncthreads();

    f32x4 acc[4][2] = {};
    for (int ks = 0; ks < 12; ++ks) {
        int tap = ks >> 2, kk = ks & 3;
        bf16x8 a[4], b[2];
#pragma unroll
        for (int m = 0; m < 4; ++m) {
            int c = wm * 64 + m * 16 + (lane & 15);
            a[m] = *(const bf16x8*)&ap[c * KD + ks * 32 + (lane >> 4) * 8];
        }
#pragma unroll
        for (int nt = 0; nt < 2; ++nt) {
            int w = wn * 32 + nt * 16 + (lane & 15);
            int q = kk * 4 + (lane >> 4);
            b[nt] = *(const bf16x8*)&smem[tap * 8192 + w * 128 + (q ^ (w & 7)) * 8];
        }
#pragma unroll
        for (int m = 0; m < 4; ++m)
#pragma unroll
            for (int nt = 0; nt < 2; ++nt)
                acc[m][nt] = __builtin_amdgcn_mfma_f32_16x16x32_bf16(a[m], b[nt], acc[m][nt], 0, 0, 0);
    }
    __syncthreads();

    // acc -> lrow[128][72] bf16 (col = w), then linear uint4 stores
    uint16_t* lrow = smem;
#pragma unroll
    for (int m = 0; m < 4; ++m)
#pragma unroll
        for (int nt = 0; nt < 2; ++nt)
#pragma unroll
            for (int r = 0; r < 4; ++r) {
                int c = wm * 64 + m * 16 + (lane >> 4) * 4 + r;
                int w = wn * 32 + nt * 16 + (lane & 15);
                lrow[c * 72 + w] = f2bf(acc[m][nt][r]);
            }
    __syncthreads();

    const uint32_t* lrowd = (const uint32_t*)smem;
    for (int t = tid; t < 1024; t += 256) {
        int c = t >> 3, ch = t & 7;
        int m0 = c * 36 + ch * 4;
        uint4 o = make_uint4(lrowd[m0], lrowd[m0 + 1], lrowd[m0 + 2], lrowd[m0 + 3]);
        *(uint4*)&t3b[(((size_t)n * C_ + c) * H_ + h) * 64 + ch * 8] = o;
    }
}

// ---------------------------------------------------------------------------
// K2: part[bx][n][c][c2] = sum_{h in chunk, w} x[c][w] * t3[c2][w + tap-1]
// bx = hc*3 + tap; NO atomics (plain stores, reduced in kr).
// ---------------------------------------------------------------------------
__global__ __launch_bounds__(512) void k2(const float* __restrict__ x,
                                          const uint16_t* __restrict__ t3b,
                                          float* __restrict__ part) {
    __shared__ uint16_t xs[128 * 64];
    __shared__ uint16_t ts[128 * 64];
    const int bx = blockIdx.x;
    const int hc = bx / 3, tap = bx - hc * 3;
    const int n = blockIdx.y;
    const int tid = threadIdx.x, lane = tid & 63, wid = tid >> 6;
    const int wm = wid >> 2, wn = wid & 3;

    f32x4 acc[4][2] = {};
    for (int hr = 0; hr < 8; ++hr) {
        const int h = hc * 8 + hr;
        __syncthreads();
        for (int t = tid; t < 1024; t += 512) {
            int c = t >> 3, qp = t & 7, q = qp ^ (c & 7);
            uint4 v = {0, 0, 0, 0};
            if (q < 7) {
                const float* s = &x[(((size_t)n * C_ + c) * H_ + h) * W_ + q * 8];
                float4 f0 = *(const float4*)s, f1 = *(const float4*)(s + 4);
                v.x = (uint32_t)f2bf(f0.x) | ((uint32_t)f2bf(f0.y) << 16);
                v.y = (uint32_t)f2bf(f0.z) | ((uint32_t)f2bf(f0.w) << 16);
                v.z = (uint32_t)f2bf(f1.x) | ((uint32_t)f2bf(f1.y) << 16);
                v.w = (uint32_t)f2bf(f1.z) | ((uint32_t)f2bf(f1.w) << 16);
            }
            *(uint4*)&xs[c * 64 + qp * 8] = v;
        }
        for (int t = tid; t < 1024; t += 512) {
            int c2 = t >> 3, qp = t & 7, q = qp ^ (c2 & 7);
            const uint16_t* row = &t3b[(((size_t)n * C_ + c2) * H_ + h) * 64];
            uint4 v = *(const uint4*)&row[q * 8];
            uint4 o;
            if (tap == 1) {
                o = v;
            } else if (tap == 2) {  // want t3[w+1]
                uint32_t nx = (q < 7) ? *(const uint32_t*)&row[q * 8 + 8] : 0u;
                o.x = (v.y << 16) | (v.x >> 16);
                o.y = (v.z << 16) | (v.y >> 16);
                o.z = (v.w << 16) | (v.z >> 16);
                o.w = (nx << 16)  | (v.w >> 16);
            } else {                // tap 0: want t3[w-1]
                uint32_t pv = (q > 0) ? *(const uint32_t*)&row[q * 8 - 2] : 0u;
                o.x = (v.x << 16) | (pv >> 16);
                o.y = (v.y << 16) | (v.x >> 16);
                o.z = (v.z << 16) | (v.y >> 16);
                o.w = (v.w << 16) | (v.z >> 16);
            }
            *(uint4*)&ts[c2 * 64 + qp * 8] = o;
        }
        __syncthreads();
#pragma unroll
        for (int ks = 0; ks < 2; ++ks) {
            bf16x8 a[4], b[2];
#pragma unroll
            for (int m = 0; m < 4; ++m) {
                int c = wm * 64 + m * 16 + (lane & 15);
                int q = ks * 4 + (lane >> 4);
                a[m] = *(const bf16x8*)&xs[c * 64 + (q ^ (c & 7)) * 8];
            }
#pragma unroll
            for (int nt = 0; nt < 2; ++nt) {
                int c2 = wn * 32 + nt * 16 + (lane & 15);
                int q = ks * 4 + (lane >> 4);
                b[nt] = *(const bf16x8*)&ts[c2 * 64 + (q ^ (c2 & 7)) * 8];
            }
#pragma unroll
            for (int m = 0; m < 4; ++m)
#pragma unroll
                for (int nt = 0; nt < 2; ++nt)
                    acc[m][nt] = __builtin_amdgcn_mfma_f32_16x16x32_bf16(a[m], b[nt], acc[m][nt], 0, 0, 0);
        }
    }
#pragma unroll
    for (int m = 0; m < 4; ++m)
#pragma unroll
        for (int nt = 0; nt < 2; ++nt)
#pragma unroll
            for (int r = 0; r < 4; ++r) {
                int c = wm * 64 + m * 16 + (lane >> 4) * 4 + r;
                int col = wn * 32 + nt * 16 + (lane & 15);
                part[((((size_t)bx * NB + n) * C_ + c) << 7) + col] = acc[m][nt][r];
            }
}

// ---------------------------------------------------------------------------
// R: t9rb[n][c][tap*128+c2] = bf16( (1/56) * sum_hc part[hc*3+tap][n][c][c2] )
// ---------------------------------------------------------------------------
__global__ __launch_bounds__(256) void kr(const float* __restrict__ part,
                                          uint16_t* __restrict__ t9rb) {
    int idx = blockIdx.x * 256 + threadIdx.x;   // 393216 threads, 4 elems each
    int fl = idx * 4;
    int nc = fl / KD, dp = fl - nc * KD;
    int tap = dp >> 7, c2 = dp & 127;
    float4 s = make_float4(0.f, 0.f, 0.f, 0.f);
#pragma unroll
    for (int hc = 0; hc < 7; ++hc) {
        const float4 v = *(const float4*)&part[((((size_t)(hc * 3 + tap)) * NB * C_ + nc) << 7) + c2];
        s.x += v.x; s.y += v.y; s.z += v.z; s.w += v.w;
    }
    const float sc = 1.f / 56.f;
    uint2 o;
    o.x = (uint32_t)f2bf(s.x * sc) | ((uint32_t)f2bf(s.y * sc) << 16);
    o.y = (uint32_t)f2bf(s.z * sc) | ((uint32_t)f2bf(s.w * sc) << 16);
    *(uint2*)&t9rb[fl] = o;
}

// ---------------------------------------------------------------------------
// K3: per-tap t12 build in 16KB LDS (lane = w, coalesced), MFMA K=128 per tap.
// grid (n fast, h slow) for p10/p5/p2 L2 reuse across the 32 n-blocks.
// ---------------------------------------------------------------------------
__global__ __launch_bounds__(256) void k3(const float* __restrict__ x,
                                          const uint16_t* __restrict__ t3b,
                                          const uint16_t* __restrict__ t9rb,
                                          const float* __restrict__ p2,
                                          const float* __restrict__ p5,
                                          const float* __restrict__ p10,
                                          float* __restrict__ out) {
    __shared__ uint16_t tsm[64 * 128];  // 16 KB per-tap buffer, 256B rows
    const int n = blockIdx.x, h = blockIdx.y, tid = threadIdx.x;
    const int lane = tid & 63, wid = tid >> 6;
    const int w = lane;
    const bool valid = (w < 56);
    const float p5v = valid ? p5[h * W_ + w] : 0.f;
    float p2v[3];
#pragma unroll
    for (int tap = 0; tap < 3; ++tap) p2v[tap] = valid ? p2[tap * W_ + w] : 0.f;

    // zero pad rows w=56..63 once (never overwritten; visible after first sync)
    if (tid < 128) {
        int wr = 56 + (tid >> 4), ch = tid & 15;
        uint4 z = {0, 0, 0, 0};
        *(uint4*)&tsm[wr * 128 + ch * 8] = z;
    }

    const int wm = wid >> 1, wn = wid & 1;
    f32x4 acc[4][2] = {};

    for (int tap = 0; tap < 3; ++tap) {
        if (tap) __syncthreads();               // prev MFMA reads done before overwrite
        const int hh = h + 2 * (tap - 1);
        const bool hok = (unsigned)hh < (unsigned)H_;
#pragma unroll
        for (int cc = 0; cc < 4; ++cc) {
            const int c2b = (wid * 4 + cc) * 8;
            uint32_t pk[4];
#pragma unroll
            for (int j = 0; j < 8; ++j) {
                int c2 = c2b + j;
                float a1 = valid ? x[(((size_t)n * C_ + c2) * H_ + h) * W_ + w] : 0.f;
                float a0 = __shfl_up(a1, 2);
                if (w < 2) a0 = 0.f;
                float a2 = __shfl_down(a1, 2);  // lanes 54,55 pull zeros from 56,57
                float mx = fmaxf(a0, fmaxf(a1, a2));
                float e0 = __expf(a0 - mx), e1 = __expf(a1 - mx), e2 = __expf(a2 - mx);
                float smv = ((tap == 0) ? e0 : (tap == 1 ? e1 : e2)) / (e0 + e1 + e2);
                float xh = (tap == 1) ? a1
                                      : ((hok && valid) ? x[(((size_t)n * C_ + c2) * H_ + hh) * W_ + w] : 0.f);
                int dor = 3 * c2 + tap;
                float t3v = valid ? bf2f(t3b[(((size_t)n * C_ + (dor & 127)) * H_ + h) * 64 + w]) : 0.f;
                float p10v = valid ? p10[((size_t)dor * H_ + h) * W_ + w] : 0.f;
                float val = p5v * t3v - p2v[tap] * xh - p10v * smv;
                uint16_t bb = f2bf(val);
                if (j & 1) pk[j >> 1] |= ((uint32_t)bb) << 16;
                else       pk[j >> 1] = bb;
            }
            int Q = c2b >> 3;   // 0..15
            if (valid) *(uint4*)&tsm[w * 128 + ((Q ^ (w & 7))) * 8] = *(const uint4*)pk;
        }
        __syncthreads();

#pragma unroll
        for (int ksub = 0; ksub < 4; ++ksub) {
            bf16x8 a[4], b[2];
#pragma unroll
            for (int m = 0; m < 4; ++m) {
                int c = wm * 64 + m * 16 + (lane & 15);
                a[m] = *(const bf16x8*)&t9rb[((size_t)n * C_ + c) * KD + tap * 128 + ksub * 32 + (lane >> 4) * 8];
            }
#pragma unroll
            for (int nt = 0; nt < 2; ++nt) {
                int ww = wn * 32 + nt * 16 + (lane & 15);
                int q = ksub * 4 + (lane >> 4);
                b[nt] = *(const bf16x8*)&tsm[ww * 128 + ((q ^ (ww & 7))) * 8];
            }
#pragma unroll
            for (int m = 0; m < 4; ++m)
#pragma unroll
                for (int nt = 0; nt < 2; ++nt)
                    acc[m][nt] = __builtin_amdgcn_mfma_f32_16x16x32_bf16(a[m], b[nt], acc[m][nt], 0, 0, 0);
        }
    }

    const float s = 0.05103103630798287f;  // 1/sqrt(384)
#pragma unroll
    for (int m = 0; m < 4; ++m)
#pragma unroll
        for (int nt = 0; nt < 2; ++nt) {
            int ww = wn * 32 + nt * 16 + (lane & 15);
            if (ww < 56) {
                int c = wm * 64 + m * 16 + (lane >> 4) * 4;
                float* dst = &out[(((size_t)n * C_ + c) * H_ + h) * W_ + ww];
#pragma unroll
                for (int r = 0; r < 4; ++r) dst[(size_t)r * HW] = acc[m][nt][r] * s;
            }
        }
}

extern "C" void kernel_launch(void* const* d_in, const int* in_sizes, int n_in,
                              void* d_out, int out_size, void* d_ws, size_t ws_size,
                              hipStream_t stream) {
    const float* x   = (const float*)d_in[0];
    const float* p2  = (const float*)d_in[1];
    const float* p3  = (const float*)d_in[2];
    const float* p5  = (const float*)d_in[3];
    const float* p10 = (const float*)d_in[4];
    float* out = (float*)d_out;

    uint8_t* w8 = (uint8_t*)d_ws;
    uint16_t* xtp  = (uint16_t*)(w8);                 // 29,360,128 B (dead after k1)
    uint16_t* t3b  = (uint16_t*)(w8 + 29360128);      // 29,360,128 B
    uint16_t* ap   = (uint16_t*)(w8 + 58720256);      //     98,304 B
    float*    part = (float*)   (w8 + 58818560);      // 44,040,192 B (end 102,858,752)
    uint16_t* t9rb = (uint16_t*)(w8);                 //  3,145,728 B (aliases dead xtp)

    p1_xtp<<<dim3(H_, NB), 256, 0, stream>>>(x, xtp);
    p2_ap<<<dim3(192), 256, 0, stream>>>(p3, ap);
    k1<<<dim3(H_, NB), 256, 0, stream>>>(xtp, ap, t3b);
    k2<<<dim3(21, NB), 512, 0, stream>>>(x, t3b, part);
    kr<<<dim3(1536), 256, 0, stream>>>(part, t9rb);
    k3<<<dim3(NB, H_), 256, 0, stream>>>(x, t3b, t9rb, p2, p5, p10, out);
}

// Round 5
// 304.689 us; speedup vs baseline: 1.3187x; 1.3187x over previous
//
#include <hip/hip_runtime.h>
#include <stdint.h>

#define NB 32
#define C_ 128
#define H_ 56
#define W_ 56
#define HW 3136
#define KD 384

typedef __attribute__((ext_vector_type(8))) short bf16x8;
typedef __attribute__((ext_vector_type(4))) float f32x4;

__device__ inline uint16_t f2bf(float f) {
    uint32_t u = __float_as_uint(f);
    return (uint16_t)((u + 0x7FFFu + ((u >> 16) & 1u)) >> 16);
}
__device__ inline float bf2f(uint16_t b) {
    return __uint_as_float(((uint32_t)b) << 16);
}

// ---------------------------------------------------------------------------
// P1: x (f32) -> xtp bf16 [n][h][w(64,pad0)][c]   (transposed for K1 B-operand)
// ---------------------------------------------------------------------------
__global__ __launch_bounds__(256) void p1_xtp(const float* __restrict__ x,
                                              uint16_t* __restrict__ xtp) {
    __shared__ uint16_t lt[56][136];
    const int h = blockIdx.x, n = blockIdx.y, tid = threadIdx.x;
    const int c = tid >> 1, wh = tid & 1;
    const float* xr = &x[(((size_t)n * C_ + c) * H_ + h) * W_ + wh * 28];
#pragma unroll
    for (int q = 0; q < 7; ++q) {
        float4 v = *(const float4*)&xr[q * 4];
        int wb = wh * 28 + q * 4;
        lt[wb + 0][c] = f2bf(v.x);
        lt[wb + 1][c] = f2bf(v.y);
        lt[wb + 2][c] = f2bf(v.z);
        lt[wb + 3][c] = f2bf(v.w);
    }
    __syncthreads();
    const int w = tid >> 2, qc = tid & 3;   // each thread owns 32 halves
    uint16_t* dst = &xtp[((((size_t)n * H_ + h) * 64 + w)) * C_ + qc * 32];
    if (w < 56) {
        const uint32_t* s = (const uint32_t*)&lt[w][qc * 32];
        uint4 a = *(const uint4*)(s);
        uint4 b = *(const uint4*)(s + 4);
        uint4 c4 = *(const uint4*)(s + 8);
        uint4 d4 = *(const uint4*)(s + 12);
        *(uint4*)dst = a;
        *(uint4*)(dst + 8) = b;
        *(uint4*)(dst + 16) = c4;
        *(uint4*)(dst + 24) = d4;
    } else {
        uint4 z = {0, 0, 0, 0};
        *(uint4*)dst = z;
        *(uint4*)(dst + 8) = z;
        *(uint4*)(dst + 16) = z;
        *(uint4*)(dst + 24) = z;
    }
}

// ---------------------------------------------------------------------------
// P2: p3 (f32 [c][3c2+tap]) -> ap bf16 [c][d'] with d' = tap*128 + c2
// ---------------------------------------------------------------------------
__global__ __launch_bounds__(256) void p2_ap(const float* __restrict__ p3,
                                             uint16_t* __restrict__ ap) {
    int i = blockIdx.x * 256 + threadIdx.x;  // < 49152
    int c = i / KD, dp = i - c * KD;
    int tap = dp >> 7, c2 = dp & 127;
    ap[i] = f2bf(p3[c * KD + 3 * c2 + tap]);
}

// ---------------------------------------------------------------------------
// K1: t3[c][w] = sum_{d'} ap[c][d'] * xtp[n][h+2(tap-1)][w][c2]   (MFMA)
// writes bf16 t3b[n][c][h][w64] (w 56..63 zero)
// ---------------------------------------------------------------------------
__global__ __launch_bounds__(256) void k1(const uint16_t* __restrict__ xtp,
                                          const uint16_t* __restrict__ ap,
                                          uint16_t* __restrict__ t3b) {
    __shared__ uint16_t smem[3 * 64 * 128];  // 48 KB; reused as lrow[128][72]
    const int h = blockIdx.x, n = blockIdx.y, tid = threadIdx.x;
    const int lane = tid & 63, wid = tid >> 6;
    const int wm = wid >> 1, wn = wid & 1;

    // stage B: 3 taps x 64 w-rows x 16 chunks (chunk-XOR swizzled, 256B rows)
    for (int t = tid; t < 3072; t += 256) {
        int tap = t >> 10, r = t & 1023, w = r >> 4, qp = r & 15;
        int q = qp ^ (w & 7);
        int hh = h + 2 * (tap - 1);
        uint4 v = {0, 0, 0, 0};
        if ((unsigned)hh < (unsigned)H_)
            v = *(const uint4*)&xtp[((((size_t)n * H_ + hh) * 64 + w)) * C_ + q * 8];
        *(uint4*)&smem[tap * 8192 + w * 128 + qp * 8] = v;
    }
    __syncthreads();

    f32x4 acc[4][2] = {};
    for (int ks = 0; ks < 12; ++ks) {
        int tap = ks >> 2, kk = ks & 3;
        bf16x8 a[4], b[2];
#pragma unroll
        for (int m = 0; m < 4; ++m) {
            int c = wm * 64 + m * 16 + (lane & 15);
            a[m] = *(const bf16x8*)&ap[c * KD + ks * 32 + (lane >> 4) * 8];
        }
#pragma unroll
        for (int nt = 0; nt < 2; ++nt) {
            int w = wn * 32 + nt * 16 + (lane & 15);
            int q = kk * 4 + (lane >> 4);
            b[nt] = *(const bf16x8*)&smem[tap * 8192 + w * 128 + (q ^ (w & 7)) * 8];
        }
#pragma unroll
        for (int m = 0; m < 4; ++m)
#pragma unroll
            for (int nt = 0; nt < 2; ++nt)
                acc[m][nt] = __builtin_amdgcn_mfma_f32_16x16x32_bf16(a[m], b[nt], acc[m][nt], 0, 0, 0);
    }
    __syncthreads();

    // acc -> lrow[128][72] bf16 (col = w), then linear uint4 stores
    uint16_t* lrow = smem;
#pragma unroll
    for (int m = 0; m < 4; ++m)
#pragma unroll
        for (int nt = 0; nt < 2; ++nt)
#pragma unroll
            for (int r = 0; r < 4; ++r) {
                int c = wm * 64 + m * 16 + (lane >> 4) * 4 + r;
                int w = wn * 32 + nt * 16 + (lane & 15);
                lrow[c * 72 + w] = f2bf(acc[m][nt][r]);
            }
    __syncthreads();

    const uint32_t* lrowd = (const uint32_t*)smem;
    for (int t = tid; t < 1024; t += 256) {
        int c = t >> 3, ch = t & 7;
        int m0 = c * 36 + ch * 4;
        uint4 o = make_uint4(lrowd[m0], lrowd[m0 + 1], lrowd[m0 + 2], lrowd[m0 + 3]);
        *(uint4*)&t3b[(((size_t)n * C_ + c) * H_ + h) * 64 + ch * 8] = o;
    }
}

// ---------------------------------------------------------------------------
// K2: part[bx][n][c][c2] = sum_{h in chunk, w} x[c][w] * t3[c2][w + tap-1]
// bx = hc*3 + tap; NO atomics (plain stores, reduced in kr).
// ---------------------------------------------------------------------------
__global__ __launch_bounds__(512) void k2(const float* __restrict__ x,
                                          const uint16_t* __restrict__ t3b,
                                          float* __restrict__ part) {
    __shared__ uint16_t xs[128 * 64];
    __shared__ uint16_t ts[128 * 64];
    const int bx = blockIdx.x;
    const int hc = bx / 3, tap = bx - hc * 3;
    const int n = blockIdx.y;
    const int tid = threadIdx.x, lane = tid & 63, wid = tid >> 6;
    const int wm = wid >> 2, wn = wid & 3;

    f32x4 acc[4][2] = {};
    for (int hr = 0; hr < 8; ++hr) {
        const int h = hc * 8 + hr;
        __syncthreads();
        for (int t = tid; t < 1024; t += 512) {
            int c = t >> 3, qp = t & 7, q = qp ^ (c & 7);
            uint4 v = {0, 0, 0, 0};
            if (q < 7) {
                const float* s = &x[(((size_t)n * C_ + c) * H_ + h) * W_ + q * 8];
                float4 f0 = *(const float4*)s, f1 = *(const float4*)(s + 4);
                v.x = (uint32_t)f2bf(f0.x) | ((uint32_t)f2bf(f0.y) << 16);
                v.y = (uint32_t)f2bf(f0.z) | ((uint32_t)f2bf(f0.w) << 16);
                v.z = (uint32_t)f2bf(f1.x) | ((uint32_t)f2bf(f1.y) << 16);
                v.w = (uint32_t)f2bf(f1.z) | ((uint32_t)f2bf(f1.w) << 16);
            }
            *(uint4*)&xs[c * 64 + qp * 8] = v;
        }
        for (int t = tid; t < 1024; t += 512) {
            int c2 = t >> 3, qp = t & 7, q = qp ^ (c2 & 7);
            const uint16_t* row = &t3b[(((size_t)n * C_ + c2) * H_ + h) * 64];
            uint4 v = *(const uint4*)&row[q * 8];
            uint4 o;
            if (tap == 1) {
                o = v;
            } else if (tap == 2) {  // want t3[w+1]
                uint32_t nx = (q < 7) ? *(const uint32_t*)&row[q * 8 + 8] : 0u;
                o.x = (v.y << 16) | (v.x >> 16);
                o.y = (v.z << 16) | (v.y >> 16);
                o.z = (v.w << 16) | (v.z >> 16);
                o.w = (nx << 16)  | (v.w >> 16);
            } else {                // tap 0: want t3[w-1]
                uint32_t pv = (q > 0) ? *(const uint32_t*)&row[q * 8 - 2] : 0u;
                o.x = (v.x << 16) | (pv >> 16);
                o.y = (v.y << 16) | (v.x >> 16);
                o.z = (v.z << 16) | (v.y >> 16);
                o.w = (v.w << 16) | (v.z >> 16);
            }
            *(uint4*)&ts[c2 * 64 + qp * 8] = o;
        }
        __syncthreads();
#pragma unroll
        for (int ks = 0; ks < 2; ++ks) {
            bf16x8 a[4], b[2];
#pragma unroll
            for (int m = 0; m < 4; ++m) {
                int c = wm * 64 + m * 16 + (lane & 15);
                int q = ks * 4 + (lane >> 4);
                a[m] = *(const bf16x8*)&xs[c * 64 + (q ^ (c & 7)) * 8];
            }
#pragma unroll
            for (int nt = 0; nt < 2; ++nt) {
                int c2 = wn * 32 + nt * 16 + (lane & 15);
                int q = ks * 4 + (lane >> 4);
                b[nt] = *(const bf16x8*)&ts[c2 * 64 + (q ^ (c2 & 7)) * 8];
            }
#pragma unroll
            for (int m = 0; m < 4; ++m)
#pragma unroll
                for (int nt = 0; nt < 2; ++nt)
                    acc[m][nt] = __builtin_amdgcn_mfma_f32_16x16x32_bf16(a[m], b[nt], acc[m][nt], 0, 0, 0);
        }
    }
#pragma unroll
    for (int m = 0; m < 4; ++m)
#pragma unroll
        for (int nt = 0; nt < 2; ++nt)
#pragma unroll
            for (int r = 0; r < 4; ++r) {
                int c = wm * 64 + m * 16 + (lane >> 4) * 4 + r;
                int col = wn * 32 + nt * 16 + (lane & 15);
                part[((((size_t)bx * NB + n) * C_ + c) << 7) + col] = acc[m][nt][r];
            }
}

// ---------------------------------------------------------------------------
// R: t9rb[n][c][tap*128+c2] = bf16( (1/56) * sum_hc part[hc*3+tap][n][c][c2] )
// ---------------------------------------------------------------------------
__global__ __launch_bounds__(256) void kr(const float* __restrict__ part,
                                          uint16_t* __restrict__ t9rb) {
    int idx = blockIdx.x * 256 + threadIdx.x;   // 393216 threads, 4 elems each
    int fl = idx * 4;
    int nc = fl / KD, dp = fl - nc * KD;
    int tap = dp >> 7, c2 = dp & 127;
    float4 s = make_float4(0.f, 0.f, 0.f, 0.f);
#pragma unroll
    for (int hc = 0; hc < 7; ++hc) {
        const float4 v = *(const float4*)&part[((((size_t)(hc * 3 + tap)) * NB * C_ + nc) << 7) + c2];
        s.x += v.x; s.y += v.y; s.z += v.z; s.w += v.w;
    }
    const float sc = 1.f / 56.f;
    uint2 o;
    o.x = (uint32_t)f2bf(s.x * sc) | ((uint32_t)f2bf(s.y * sc) << 16);
    o.y = (uint32_t)f2bf(s.z * sc) | ((uint32_t)f2bf(s.w * sc) << 16);
    *(uint2*)&t9rb[fl] = o;
}

// ---------------------------------------------------------------------------
// K3: single-phase t12 build (lane = w, all taps together, softmax once) into
// a full [64 w][384 k] LDS tile (768B rows, XOR-16B-chunk swizzle), then
// 12-kstep MFMA. Grid (n fast, h slow) for p10/p5/p2 L2 reuse.
// ---------------------------------------------------------------------------
__global__ __launch_bounds__(256) void k3(const float* __restrict__ x,
                                          const uint16_t* __restrict__ t3b,
                                          const uint16_t* __restrict__ t9rb,
                                          const float* __restrict__ p2,
                                          const float* __restrict__ p5,
                                          const float* __restrict__ p10,
                                          float* __restrict__ out) {
    __shared__ uint16_t tsm[64 * 384];  // 48 KB
    const int n = blockIdx.x, h = blockIdx.y, tid = threadIdx.x;
    const int lane = tid & 63, wid = tid >> 6;
    const int w = lane;
    const bool valid = (w < 56);
    const int wsw = (w & 7) << 3;       // u16-index XOR mask for this row
    const float p5v = valid ? p5[h * W_ + w] : 0.f;
    float p2v[3];
#pragma unroll
    for (int tap = 0; tap < 3; ++tap) p2v[tap] = valid ? p2[tap * W_ + w] : 0.f;

    // zero pad rows w=56..63 (full 384 cols; written once, before first sync)
    for (int t = tid; t < 384; t += 256) {
        int wr = 56 + t / 48, ch = t - (t / 48) * 48;
        uint4 z = {0, 0, 0, 0};
        *(uint4*)&tsm[wr * 384 + ch * 8] = z;
    }

    // ---- single build phase: all 3 taps, softmax computed once per c2 ----
#pragma unroll 2
    for (int cc = 0; cc < 4; ++cc) {
        const int c2b = (wid * 4 + cc) * 8;
        float xc[8], sm0[8], sm1[8], sm2[8];
#pragma unroll
        for (int j = 0; j < 8; ++j) {
            int c2 = c2b + j;
            float a1 = valid ? x[(((size_t)n * C_ + c2) * H_ + h) * W_ + w] : 0.f;
            xc[j] = a1;
            float a0 = __shfl_up(a1, 2);
            if (w < 2) a0 = 0.f;
            float a2 = __shfl_down(a1, 2);  // lanes 54,55 pull zeros from 56,57
            float mx = fmaxf(a0, fmaxf(a1, a2));
            float e0 = __expf(a0 - mx), e1 = __expf(a1 - mx), e2 = __expf(a2 - mx);
            float rs = 1.f / (e0 + e1 + e2);
            sm0[j] = e0 * rs; sm1[j] = e1 * rs; sm2[j] = e2 * rs;
        }
#pragma unroll
        for (int tap = 0; tap < 3; ++tap) {
            const int hh = h + 2 * (tap - 1);
            const bool hok = (unsigned)hh < (unsigned)H_;
            uint32_t pk[4];
#pragma unroll
            for (int j = 0; j < 8; ++j) {
                int c2 = c2b + j;
                float xh = (tap == 1) ? xc[j]
                                      : ((hok && valid) ? x[(((size_t)n * C_ + c2) * H_ + hh) * W_ + w] : 0.f);
                int dor = 3 * c2 + tap;
                float t3v = valid ? bf2f(t3b[(((size_t)n * C_ + (dor & 127)) * H_ + h) * 64 + w]) : 0.f;
                float p10v = valid ? p10[((size_t)dor * H_ + h) * W_ + w] : 0.f;
                float smv = (tap == 0) ? sm0[j] : (tap == 1 ? sm1[j] : sm2[j]);
                float val = p5v * t3v - p2v[tap] * xh - p10v * smv;
                uint16_t bb = f2bf(val);
                if (j & 1) pk[j >> 1] |= ((uint32_t)bb) << 16;
                else       pk[j >> 1] = bb;
            }
            int kcol = tap * 128 + c2b;     // 8-aligned column block in d'
            if (valid) *(uint4*)&tsm[w * 384 + (kcol ^ wsw)] = *(const uint4*)pk;
        }
    }
    __syncthreads();

    // ---- MFMA: out[c][w] = sum_k t9rb[c][k] * tsm[w][k] ----
    const int wm = wid >> 1, wn = wid & 1;
    f32x4 acc[4][2] = {};
    for (int ks = 0; ks < 12; ++ks) {
        bf16x8 a[4], b[2];
#pragma unroll
        for (int m = 0; m < 4; ++m) {
            int c = wm * 64 + m * 16 + (lane & 15);
            a[m] = *(const bf16x8*)&t9rb[((size_t)n * C_ + c) * KD + ks * 32 + (lane >> 4) * 8];
        }
#pragma unroll
        for (int nt = 0; nt < 2; ++nt) {
            int ww = wn * 32 + nt * 16 + (lane & 15);
            int k0 = ks * 32 + (lane >> 4) * 8;
            b[nt] = *(const bf16x8*)&tsm[ww * 384 + (k0 ^ ((ww & 7) << 3))];
        }
#pragma unroll
        for (int m = 0; m < 4; ++m)
#pragma unroll
            for (int nt = 0; nt < 2; ++nt)
                acc[m][nt] = __builtin_amdgcn_mfma_f32_16x16x32_bf16(a[m], b[nt], acc[m][nt], 0, 0, 0);
    }

    const float s = 0.05103103630798287f;  // 1/sqrt(384)
#pragma unroll
    for (int m = 0; m < 4; ++m)
#pragma unroll
        for (int nt = 0; nt < 2; ++nt) {
            int ww = wn * 32 + nt * 16 + (lane & 15);
            if (ww < 56) {
                int c = wm * 64 + m * 16 + (lane >> 4) * 4;
                float* dst = &out[(((size_t)n * C_ + c) * H_ + h) * W_ + ww];
#pragma unroll
                for (int r = 0; r < 4; ++r) dst[(size_t)r * HW] = acc[m][nt][r] * s;
            }
        }
}

extern "C" void kernel_launch(void* const* d_in, const int* in_sizes, int n_in,
                              void* d_out, int out_size, void* d_ws, size_t ws_size,
                              hipStream_t stream) {
    const float* x   = (const float*)d_in[0];
    const float* p2  = (const float*)d_in[1];
    const float* p3  = (const float*)d_in[2];
    const float* p5  = (const float*)d_in[3];
    const float* p10 = (const float*)d_in[4];
    float* out = (float*)d_out;

    uint8_t* w8 = (uint8_t*)d_ws;
    uint16_t* xtp  = (uint16_t*)(w8);                 // 29,360,128 B (dead after k1)
    uint16_t* t3b  = (uint16_t*)(w8 + 29360128);      // 29,360,128 B
    uint16_t* ap   = (uint16_t*)(w8 + 58720256);      //     98,304 B
    float*    part = (float*)   (w8 + 58818560);      // 44,040,192 B (end 102,858,752)
    uint16_t* t9rb = (uint16_t*)(w8);                 //  3,145,728 B (aliases dead xtp)

    p1_xtp<<<dim3(H_, NB), 256, 0, stream>>>(x, xtp);
    p2_ap<<<dim3(192), 256, 0, stream>>>(p3, ap);
    k1<<<dim3(H_, NB), 256, 0, stream>>>(xtp, ap, t3b);
    k2<<<dim3(21, NB), 512, 0, stream>>>(x, t3b, part);
    kr<<<dim3(1536), 256, 0, stream>>>(part, t9rb);
    k3<<<dim3(NB, H_), 256, 0, stream>>>(x, t3b, t9rb, p2, p5, p10, out);
}